// Round 9
// baseline (48.344 us; speedup 1.0000x reference)
//
#include <hip/hip_runtime.h>

#define B_      2
#define NCH     4
#define DIMX    18
#define NPT     (18*18*18)        /* 5832 */
#define TIL     183               /* j-tiles of 32 */
#define ITIL    184               /* i-tiles incl pad */
#define NPTP    (ITIL*32)         /* 5888 */
#define IBLOCKS 23                /* 8 i-tiles per block (2 per wave) */
#define JSP     22                /* j splits: 23*22*2 = 1012 blocks ~ 4/CU */
#define NB      (IBLOCKS*JSP*B_)
#define MAXT    9                 /* max tiles per j-chunk */
#define FSC     (1.2011224087864498f / 5.0f)   /* sqrt(log2 e)/5 */
#define QPAD    -30000.0f

typedef __attribute__((ext_vector_type(8)))  short short8;
typedef __attribute__((ext_vector_type(16))) float f32x16;
typedef __attribute__((ext_vector_type(4)))  int   int4_;

#define EXP2(x) __builtin_amdgcn_exp2f(x)
#define MFMA32(a, b, c) __builtin_amdgcn_mfma_f32_32x32x16_bf16(a, b, c, 0, 0, 0)

__device__ __forceinline__ unsigned short bf16rtn(float f) {
  unsigned u = __float_as_uint(f);
  u += 0x7fffu + ((u >> 16) & 1u);
  return (unsigned short)(u >> 16);
}
__device__ __forceinline__ float bf2f(unsigned short s) {
  return __uint_as_float(((unsigned)s) << 16);
}

__device__ __forceinline__ float blockReduceSum(float v) {
  #pragma unroll
  for (int o = 32; o > 0; o >>= 1) v += __shfl_down(v, o, 64);
  __shared__ float red[4];
  int wid = threadIdx.x >> 6, lane = threadIdx.x & 63;
  if (lane == 0) red[wid] = v;
  __syncthreads();
  v = (threadIdx.x < 4) ? red[threadIdx.x] : 0.0f;
  if (wid == 0) {
    v += __shfl_down(v, 2, 64);
    v += __shfl_down(v, 1, 64);
  }
  __syncthreads();
  return v;  // valid on thread 0
}

// features for point n: f0..f5 (pre-scaled), q = -0.5*|f|^2
__device__ __forceinline__ void feat6(const float* __restrict__ I, int bb, int n,
                                      float f[6], float* q) {
  int x = n / (DIMX * DIMX);
  int rem = n - x * DIMX * DIMX;
  int y = rem / DIMX, zz = rem - y * DIMX;
  f[0] = x * FSC; f[1] = y * FSC; f[2] = zz * FSC;
  f[3] = I[(size_t)(bb * 3 + 0) * NPT + n] * FSC;
  f[4] = I[(size_t)(bb * 3 + 1) * NPT + n] * FSC;
  f[5] = I[(size_t)(bb * 3 + 2) * NPT + n] * FSC;
  *q = -0.5f * (f[0]*f[0] + f[1]*f[1] + f[2]*f[2] + f[3]*f[3] + f[4]*f[4] + f[5]*f[5]);
}

// j-side b-vector (f0..f5, 1, q) as hi/lo bf16 split; pad -> w=0 sentinel
__device__ __forceinline__ void bfeat(const float* __restrict__ I, int bb, int n,
                                      short8* hi, short8* lo) {
  short8 h_ = {0,0,0,0,0,0,0,0}, l_ = {0,0,0,0,0,0,0,0};
  if (n < NPT) {
    float f[6], q;
    feat6(I, bb, n, f, &q);
    float bv[8] = {f[0], f[1], f[2], f[3], f[4], f[5], 1.0f, q};
    #pragma unroll
    for (int e = 0; e < 8; ++e) {
      unsigned short bh = bf16rtn(bv[e]);
      h_[e] = (short)bh;
      l_[e] = (short)bf16rtn(bv[e] - bf2f(bh));
    }
  } else {
    h_[7] = (short)bf16rtn(QPAD);
  }
  *hi = h_; *lo = l_;
}

// i-side a-vector (f0..f5, q, 1) hi bf16 only; pad -> 0
__device__ __forceinline__ short8 afeat(const float* __restrict__ I, int bb, int n) {
  short8 a = {0,0,0,0,0,0,0,0};
  if (n < NPT) {
    float f[6], q;
    feat6(I, bb, n, f, &q);
    float av[8] = {f[0], f[1], f[2], f[3], f[4], f[5], q, 1.0f};
    #pragma unroll
    for (int e = 0; e < 8; ++e) a[e] = (short)bf16rtn(av[e]);
  }
  return a;
}

__device__ __forceinline__ float4 softmax4(const float* __restrict__ U, int bb, int n) {
  float u0 = U[(size_t)(bb * NCH + 0) * NPT + n];
  float u1 = U[(size_t)(bb * NCH + 1) * NPT + n];
  float u2 = U[(size_t)(bb * NCH + 2) * NPT + n];
  float u3 = U[(size_t)(bb * NCH + 3) * NPT + n];
  float m = fmaxf(fmaxf(u0, u1), fmaxf(u2, u3));
  float e0 = __expf(u0-m), e1 = __expf(u1-m), e2 = __expf(u2-m), e3 = __expf(u3-m);
  float inv = 1.0f / (e0 + e1 + e2 + e3);
  return make_float4(e0*inv, e1*inv, e2*inv, e3*inv);
}

__device__ __forceinline__ float expsum16(const f32x16 acc) {
  float e[16];
  #pragma unroll
  for (int r = 0; r < 16; ++r) e[r] = EXP2(acc[r]);
  float s8[8];
  #pragma unroll
  for (int r = 0; r < 8; ++r) s8[r] = e[2*r] + e[2*r+1];
  float s4[4];
  #pragma unroll
  for (int r = 0; r < 4; ++r) s4[r] = s8[2*r] + s8[2*r+1];
  return (s4[0] + s4[1]) + (s4[2] + s4[3]);
}

// ---------------- pass1 (prep fused) ----------------
__global__ void __launch_bounds__(256, 4) pass1_kernel(const float* __restrict__ I,
                                                       float* __restrict__ part) {
  __shared__ short8 bhl[MAXT * 32 * 2];   /* [point][hi|lo] */
  int tid = threadIdx.x, wid = tid >> 6, l = tid & 63, h = l >> 5, li = l & 31;
  int bb = blockIdx.z, jc = blockIdx.y, ib = blockIdx.x;
  int t0 = jc * TIL / JSP, t1 = (jc + 1) * TIL / JSP;
  int cnt = (t1 - t0) * 32;

  for (int p = tid; p < cnt; p += 256) {
    short8 hi, lo;
    bfeat(I, bb, t0 * 32 + p, &hi, &lo);
    bhl[p * 2]     = hi;
    bhl[p * 2 + 1] = lo;
  }

  int i0 = (ib * 8 + wid) * 32 + li;
  int i1 = i0 + 128;
  short8 b1_0 = afeat(I, bb, i0);
  short8 b1_1 = afeat(I, bb, i1);
  __syncthreads();

  f32x16 z;
  #pragma unroll
  for (int r = 0; r < 16; ++r) z[r] = 0.0f;

  float sacc0 = 0.0f, sacc1 = 0.0f;
  for (int t = t0; t < t1; ++t) {
    short8 a = bhl[((t - t0) * 32 + li) * 2 + h];
    f32x16 acc0 = MFMA32(a, b1_0, z);
    f32x16 acc1 = MFMA32(a, b1_1, z);
    sacc0 += expsum16(acc0);
    sacc1 += expsum16(acc1);
  }
  sacc0 += __shfl_xor(sacc0, 32, 64);
  sacc1 += __shfl_xor(sacc1, 32, 64);
  if (h == 0) {
    part[((size_t)bb * JSP + jc) * NPTP + i0] = sacc0;
    part[((size_t)bb * JSP + jc) * NPTP + i1] = sacc1;
  }
}

// ---------------- pass2 (finalize + reduce fused) ----------------
__global__ void __launch_bounds__(256, 4) pass2_kernel(const float* __restrict__ I,
                                                       const float* __restrict__ U,
                                                       const float* __restrict__ part,
                                                       float* __restrict__ pl,
                                                       unsigned* __restrict__ cnt_,
                                                       float* __restrict__ out) {
  __shared__ short8 bhl[MAXT * 32 * 2];
  __shared__ short8 vt8[MAXT * 4 * 4];    /* [tile][c][group] 16B frags */
  __shared__ bool isLast;
  int tid = threadIdx.x, wid = tid >> 6, l = tid & 63, h = l >> 5, li = l & 31;
  int bb = blockIdx.z, jc = blockIdx.y, ib = blockIdx.x;
  int t0 = jc * TIL / JSP, t1 = (jc + 1) * TIL / JSP;
  int cnt = (t1 - t0) * 32;
  unsigned short* vtp = (unsigned short*)vt8;

  for (int p = tid; p < cnt; p += 256) {
    int j = t0 * 32 + p;
    short8 hi, lo;
    bfeat(I, bb, j, &hi, &lo);
    bhl[p * 2]     = hi;
    bhl[p * 2 + 1] = lo;
    float4 hv = make_float4(0.f, 0.f, 0.f, 0.f);
    float nrm = 0.0f;
    if (j < NPT) {
      float s = 0.0f;
      #pragma unroll
      for (int k = 0; k < JSP; ++k) s += part[((size_t)bb * JSP + k) * NPTP + j];
      nrm = rsqrtf(s + 1e-20f);
      hv = softmax4(U, bb, j);
    }
    int tt = p >> 5, jj = p & 31;
    int g1 = jj >> 4, r = jj & 15;
    int slot = (g1 * 2 + ((r >> 2) & 1)) * 8 + (r & 3) + 4 * (r >> 3);
    vtp[(tt * 4 + 0) * 32 + slot] = bf16rtn(hv.x * nrm);
    vtp[(tt * 4 + 1) * 32 + slot] = bf16rtn(hv.y * nrm);
    vtp[(tt * 4 + 2) * 32 + slot] = bf16rtn(hv.z * nrm);
    vtp[(tt * 4 + 3) * 32 + slot] = bf16rtn(hv.w * nrm);
  }

  int i0 = (ib * 8 + wid) * 32 + li;
  int i1 = i0 + 128;
  short8 b1_0 = afeat(I, bb, i0);
  short8 b1_1 = afeat(I, bb, i1);
  float4 g0 = make_float4(0.f, 0.f, 0.f, 0.f), g1v = g0;
  {
    if (i0 < NPT) {
      float s = 0.0f;
      #pragma unroll
      for (int k = 0; k < JSP; ++k) s += part[((size_t)bb * JSP + k) * NPTP + i0];
      float nrm = rsqrtf(s + 1e-20f);
      float4 hh = softmax4(U, bb, i0);
      g0 = make_float4((1.f-hh.x)*nrm, (1.f-hh.y)*nrm, (1.f-hh.z)*nrm, (1.f-hh.w)*nrm);
    }
    if (i1 < NPT) {
      float s = 0.0f;
      #pragma unroll
      for (int k = 0; k < JSP; ++k) s += part[((size_t)bb * JSP + k) * NPTP + i1];
      float nrm = rsqrtf(s + 1e-20f);
      float4 hh = softmax4(U, bb, i1);
      g1v = make_float4((1.f-hh.x)*nrm, (1.f-hh.y)*nrm, (1.f-hh.z)*nrm, (1.f-hh.w)*nrm);
    }
  }
  __syncthreads();

  const short8 zer = {0, 0, 0, 0, 0, 0, 0, 0};
  bool cok = li < 4;
  int cc = cok ? li : 0;

  f32x16 z;
  #pragma unroll
  for (int r = 0; r < 16; ++r) z[r] = 0.0f;
  f32x16 d2_0 = z, d2_1 = z;

  for (int t = t0; t < t1; ++t) {
    int tt = t - t0;
    short8 a = bhl[(tt * 32 + li) * 2 + h];
    short8 vf1 = vt8[(tt * 4 + cc) * 4 + h];
    short8 vf2 = vt8[(tt * 4 + cc) * 4 + 2 + h];
    vf1 = cok ? vf1 : zer;
    vf2 = cok ? vf2 : zer;

    f32x16 acc0 = MFMA32(a, b1_0, z);
    f32x16 acc1 = MFMA32(a, b1_1, z);

    float w0[16], w1[16];
    #pragma unroll
    for (int r = 0; r < 16; ++r) { w0[r] = EXP2(acc0[r]); w1[r] = EXP2(acc1[r]); }
    int p0[8], p1[8];
    #pragma unroll
    for (int r = 0; r < 8; ++r) {
      asm("v_cvt_pk_bf16_f32 %0, %1, %2" : "=v"(p0[r]) : "v"(w0[2*r]), "v"(w0[2*r+1]));
      asm("v_cvt_pk_bf16_f32 %0, %1, %2" : "=v"(p1[r]) : "v"(w1[2*r]), "v"(w1[2*r+1]));
    }
    union { int4_ iv; short8 sv; } u1a, u2a, u1b, u2b;
    u1a.iv = (int4_){p0[0], p0[1], p0[2], p0[3]};
    u2a.iv = (int4_){p0[4], p0[5], p0[6], p0[7]};
    u1b.iv = (int4_){p1[0], p1[1], p1[2], p1[3]};
    u2b.iv = (int4_){p1[4], p1[5], p1[6], p1[7]};

    d2_0 = MFMA32(vf1, u1a.sv, d2_0);
    d2_0 = MFMA32(vf2, u2a.sv, d2_0);
    d2_1 = MFMA32(vf1, u1b.sv, d2_1);
    d2_1 = MFMA32(vf2, u2b.sv, d2_1);
  }

  float loss = d2_0[0] * g0.x + d2_0[1] * g0.y + d2_0[2] * g0.z + d2_0[3] * g0.w
             + d2_1[0] * g1v.x + d2_1[1] * g1v.y + d2_1[2] * g1v.z + d2_1[3] * g1v.w;
  float r = blockReduceSum(loss);

  int blkflat = ((bb * JSP + jc) * IBLOCKS + ib);
  if (tid == 0) {
    pl[blkflat] = r;
    __threadfence();
    unsigned prev = atomicAdd(cnt_, 1u);
    isLast = (prev == NB - 1);
  }
  __syncthreads();
  if (isLast) {
    __threadfence();
    float v = 0.0f;
    for (int k = tid; k < NB; k += 256) v += pl[k];
    float rr = blockReduceSum(v);
    if (tid == 0) out[0] = rr;
  }
}

extern "C" void kernel_launch(void* const* d_in, const int* in_sizes, int n_in,
                              void* d_out, int out_size, void* d_ws, size_t ws_size,
                              hipStream_t stream) {
  const float* I = (const float*)d_in[0];
  const float* U = (const float*)d_in[1];
  float* out = (float*)d_out;

  char* w = (char*)d_ws;
  float* part = (float*)w;          w += (size_t)B_ * JSP * NPTP * 4;
  float* pl   = (float*)w;          w += (size_t)NB * 4;
  unsigned* cnt_ = (unsigned*)w;    w += 64;

  hipMemsetAsync(cnt_, 0, 4, stream);
  dim3 grid(IBLOCKS, JSP, B_);
  pass1_kernel<<<grid, 256, 0, stream>>>(I, part);
  pass2_kernel<<<grid, 256, 0, stream>>>(I, U, part, pl, cnt_, out);
}